// Round 4
// baseline (145.129 us; speedup 1.0000x reference)
//
#include <hip/hip_runtime.h>

// B=32, T=2048, D=128, H=256. fp32 in/out. SINGLE dispatch.
// 2-phase, 2-barrier wave-specialized megakernel, grid (8,32), 512 threads.
// Chunk = 256 t (seams at 256-t granularity only: finer chunking fails
// numerically), warmup = 128 t, subchunk = 16 t, 24 subchunks (+ epilogue).
// Steady state per subchunk s:
//   phase B: S(w0-3): scan1(s)          | w4-5: scan2(s-1) | w6-7: stage x(s+1)
//   BAR_LDS
//   phase A: S: GEMM2(s)->h2            | G: GEMM1(s+1)->h1, pfx prefetch
//            all: pfln prefetch(s), LN(s-1)+store
//   BAR_LDS
// KEY CHANGE vs R3: barriers are raw {s_waitcnt lgkmcnt(0); s_barrier}
// instead of __syncthreads(). __syncthreads' implicit vmcnt(0) drain was
// forcing LN stores + pfx/pfln register prefetches to retire at every
// barrier (~2x HBM latency per iteration on the critical path). The only
// ordering these barriers must provide is LDS visibility -> lgkmcnt(0)
// suffices (out is write-only; prefetches are register loads).
// All accumulation orders instruction-identical to R0 (absmax 0.015625).
//
// LDS 50,688 B:
//   h1buf[16*260] f32 (16,640)  h2buf[16*132] f32 (8,448)
//   s2buf[16*132] f32 (8,448)   spkbuf[16*264] fp16 (8,448)
//   xb[2][16*136] fp16 (17,408)

typedef _Float16 half8 __attribute__((ext_vector_type(8)));
typedef float f32x4 __attribute__((ext_vector_type(4)));

#define MFMA_F16(a, b, c) __builtin_amdgcn_mfma_f32_16x16x32_f16(a, b, c, 0, 0, 0)

__device__ __forceinline__ void bar_lds() {
    // LDS-only barrier: complete this wave's outstanding DS ops, then rendezvous.
    // Deliberately does NOT drain vmcnt (global stores / register prefetches
    // stay in flight across the barrier).
    asm volatile("s_waitcnt lgkmcnt(0)" ::: "memory");
    __builtin_amdgcn_s_barrier();
    __builtin_amdgcn_sched_barrier(0);   // rule #18: no hoisting across the wait
}

__device__ __forceinline__ unsigned short h2u(_Float16 h) {
    union { _Float16 h; unsigned short u; } x; x.h = h; return x.u;
}

__device__ __forceinline__ void split8(float4 f0, float4 f1, half8& a, half8& b) {
    float fs[8] = {f0.x, f0.y, f0.z, f0.w, f1.x, f1.y, f1.z, f1.w};
    half8 ha, hb;
#pragma unroll
    for (int q = 0; q < 8; ++q) {
        ha[q] = (_Float16)fs[q];
        hb[q] = (_Float16)(fs[q] - (float)ha[q]);
    }
    a = ha; b = hb;
}

__global__ __launch_bounds__(512, 1) void mega_kernel(
    const float* __restrict__ X,
    const float* __restrict__ W1, const float* __restrict__ W2,
    const float* __restrict__ b1, const float* __restrict__ b2,
    const float* __restrict__ lnw, const float* __restrict__ lnb,
    float* __restrict__ out)
{
    __shared__ __align__(16) float h1buf[16 * 260];                 // 16,640 B
    __shared__ __align__(16) float h2buf[16 * 132];                 //  8,448 B
    __shared__ __align__(16) float s2buf[16 * 132];                 //  8,448 B
    __shared__ __align__(16) unsigned short spkbuf[16 * 264];       //  8,448 B
    __shared__ __align__(16) unsigned short xb[2][16 * 136];        // 17,408 B

    const int tid = threadIdx.x;
    const int lane = tid & 63;
    const int w = tid >> 6;                 // wave 0..7
    const bool isS = (tid < 256);           // S-group: waves 0-3
    const int sg = w;                       // S-wave id
    const int gg = w - 4;                   // G-wave id
    const int fr = lane & 15;
    const int fo8 = (lane >> 4) * 8;
    const int qr = (lane >> 4) * 4;
    const int b = blockIdx.y;
    const int t0 = blockIdx.x * 256;
    const int s0 = (blockIdx.x == 0) ? 8 : 0;

    const float* __restrict__ xbase = X + (size_t)b * 2048 * 128;
    float* __restrict__ obase = out + (size_t)b * 2048 * 128;

    // ---- shared-physical weight fragments (identical to R0) ----
    half8 wf[32];
    float bias0[4];
    if (isS) {
        // W2 slice: d-rows 32sg+16j+fr, j<2; wf[(j*8+ks)*2+p]
#pragma unroll
        for (int j = 0; j < 2; ++j) {
            const size_t d = (size_t)(32 * sg + 16 * j + fr) * 256;
#pragma unroll
            for (int ks = 0; ks < 8; ++ks) {
                float4 f0 = *(const float4*)&W2[d + ks * 32 + fo8];
                float4 f1 = *(const float4*)&W2[d + ks * 32 + fo8 + 4];
                split8(f0, f1, wf[(j * 8 + ks) * 2], wf[(j * 8 + ks) * 2 + 1]);
            }
            bias0[j] = b2[32 * sg + 16 * j + fr];
        }
    } else {
        // W1 slice: h-rows 64gg+16j+fr, j<4; wf[(j*4+k0)*2+p]
#pragma unroll
        for (int j = 0; j < 4; ++j) {
            const size_t n = (size_t)(64 * gg + 16 * j + fr) * 128;
#pragma unroll
            for (int k0 = 0; k0 < 4; ++k0) {
                float4 f0 = *(const float4*)&W1[n + k0 * 32 + fo8];
                float4 f1 = *(const float4*)&W1[n + k0 * 32 + fo8 + 4];
                split8(f0, f1, wf[(j * 4 + k0) * 2], wf[(j * 4 + k0) * 2 + 1]);
            }
            bias0[j] = b1[64 * gg + 16 * j + fr];
        }
    }
    const float2 wv = *(const float2*)(lnw + lane * 2);
    const float2 bbv = *(const float2*)(lnb + lane * 2);

    float v1 = 0.0f, v2 = 0.0f;
    const int d2 = (tid - 256) & 127;       // scan2 col (waves 4-5)
    const int tgs = (tid - 384) & 127;      // stage thread idx (waves 6-7)
    const int srow = tgs >> 5;              // 0..3
    const int sc4 = (tgs & 31) * 4;         // 0..124
    float4 pfx[4];
    float2 pflnC[2], pflnN[2];

    // ---- prologue: stage x(s0); GEMM1(s0); prime pfx for x(s0+1) ----
    if (tid >= 384) {
        const int tb = t0 - 128 + s0 * 16;
#pragma unroll
        for (int q = 0; q < 4; ++q) {
            float4 xv = *(const float4*)&xbase[(size_t)(tb + srow + 4 * q) * 128 + sc4];
            _Float16 a0 = (_Float16)xv.x, e0 = (_Float16)(xv.x - (float)a0);
            _Float16 a1 = (_Float16)xv.y, e1 = (_Float16)(xv.y - (float)a1);
            _Float16 a2 = (_Float16)xv.z, e2 = (_Float16)(xv.z - (float)a2);
            _Float16 a3 = (_Float16)xv.w, e3 = (_Float16)(xv.w - (float)a3);
            ushort4 ua = {h2u(a0), h2u(a1), h2u(a2), h2u(a3)};
            ushort4 ue = {h2u(e0), h2u(e1), h2u(e2), h2u(e3)};
            *(ushort4*)&xb[0][(srow + 4 * q) * 136 + sc4] = ua;
            *(ushort4*)&xb[1][(srow + 4 * q) * 136 + sc4] = ue;
        }
    }
    bar_lds();
    if (!isS) {
        const _Float16* xa0 = (const _Float16*)&xb[0][0];
        const _Float16* xa1 = (const _Float16*)&xb[1][0];
        f32x4 acc[4];
#pragma unroll
        for (int j = 0; j < 4; ++j) acc[j] = (f32x4){0.f, 0.f, 0.f, 0.f};
#pragma unroll
        for (int k0 = 0; k0 < 4; ++k0) {
            half8 a0 = *(const half8*)&xa0[fr * 136 + k0 * 32 + fo8];
            half8 a1 = *(const half8*)&xa1[fr * 136 + k0 * 32 + fo8];
#pragma unroll
            for (int j = 0; j < 4; ++j) {
                acc[j] = MFMA_F16(a0, wf[(j * 4 + k0) * 2], acc[j]);
                acc[j] = MFMA_F16(a0, wf[(j * 4 + k0) * 2 + 1], acc[j]);
                acc[j] = MFMA_F16(a1, wf[(j * 4 + k0) * 2], acc[j]);
            }
        }
#pragma unroll
        for (int j = 0; j < 4; ++j) {
            int col = 64 * gg + 16 * j + fr;
#pragma unroll
            for (int r = 0; r < 4; ++r)
                h1buf[(qr + r) * 260 + col] = acc[j][r] + bias0[j];
        }
        if (tid >= 384) {
            const int tb = t0 - 128 + s0 * 16 + 16;
#pragma unroll
            for (int q = 0; q < 4; ++q)
                pfx[q] = *(const float4*)&xbase[(size_t)(tb + srow + 4 * q) * 128 + sc4];
        }
    }
    bar_lds();

    // ---- main loop: s0..24 (s=24 runs only scan2(23)/LN(23)) ----
    for (int s = s0; s <= 24; ++s) {
        const int tbase = t0 - 128 + s * 16;

        // ================= phase B =================
        if (isS) {
            if (s <= 23) {
                // scan1(s): h1 -> spikes
                float hh[16];
#pragma unroll
                for (int t = 0; t < 16; ++t) hh[t] = h1buf[t * 260 + tid];
#pragma unroll
                for (int t = 0; t < 16; ++t) {
                    float h = v1 + (hh[t] - v1) * 0.5f;
                    bool sp = (h >= 1.0f);
                    v1 = sp ? 0.0f : h;
                    spkbuf[t * 264 + tid] = sp ? (unsigned short)0x3C00 : (unsigned short)0;
                }
            }
        } else if (tid < 384) {
            if (s > s0) {
                // scan2(s-1): h2 -> s2
                float hh[16];
#pragma unroll
                for (int t = 0; t < 16; ++t) hh[t] = h2buf[t * 132 + d2];
#pragma unroll
                for (int t = 0; t < 16; ++t) {
                    float h = v2 + (hh[t] - v2) * 0.5f;
                    bool sp = (h >= 1.0f);
                    v2 = sp ? 0.0f : h;
                    s2buf[t * 132 + d2] = sp ? 1.0f : 0.0f;
                }
            }
        } else {
            if (s <= 22) {
                // stage x(s+1) from pfx regs
#pragma unroll
                for (int q = 0; q < 4; ++q) {
                    float4 xv = pfx[q];
                    _Float16 a0 = (_Float16)xv.x, e0 = (_Float16)(xv.x - (float)a0);
                    _Float16 a1 = (_Float16)xv.y, e1 = (_Float16)(xv.y - (float)a1);
                    _Float16 a2 = (_Float16)xv.z, e2 = (_Float16)(xv.z - (float)a2);
                    _Float16 a3 = (_Float16)xv.w, e3 = (_Float16)(xv.w - (float)a3);
                    ushort4 ua = {h2u(a0), h2u(a1), h2u(a2), h2u(a3)};
                    ushort4 ue = {h2u(e0), h2u(e1), h2u(e2), h2u(e3)};
                    *(ushort4*)&xb[0][(srow + 4 * q) * 136 + sc4] = ua;
                    *(ushort4*)&xb[1][(srow + 4 * q) * 136 + sc4] = ue;
                }
            }
        }
        bar_lds();

        // ================= phase A =================
        if (isS) {
            if (s <= 23) {
                // GEMM2(s): spikes @ W2 -> h2
                const _Float16* sp = (const _Float16*)&spkbuf[0];
                f32x4 acc[2];
                acc[0] = (f32x4){0.f, 0.f, 0.f, 0.f};
                acc[1] = (f32x4){0.f, 0.f, 0.f, 0.f};
#pragma unroll
                for (int ks = 0; ks < 8; ++ks) {
                    half8 a = *(const half8*)&sp[fr * 264 + ks * 32 + fo8];
#pragma unroll
                    for (int j = 0; j < 2; ++j) {
                        acc[j] = MFMA_F16(a, wf[(j * 8 + ks) * 2], acc[j]);
                        acc[j] = MFMA_F16(a, wf[(j * 8 + ks) * 2 + 1], acc[j]);
                    }
                }
#pragma unroll
                for (int j = 0; j < 2; ++j) {
                    int col = 32 * sg + 16 * j + fr;
#pragma unroll
                    for (int r = 0; r < 4; ++r)
                        h2buf[(qr + r) * 132 + col] = acc[j][r] + bias0[j];
                }
            }
        } else {
            if (s <= 22) {
                // GEMM1(s+1): x(s+1) @ W1 -> h1
                const _Float16* xa0 = (const _Float16*)&xb[0][0];
                const _Float16* xa1 = (const _Float16*)&xb[1][0];
                f32x4 acc[4];
#pragma unroll
                for (int j = 0; j < 4; ++j) acc[j] = (f32x4){0.f, 0.f, 0.f, 0.f};
#pragma unroll
                for (int k0 = 0; k0 < 4; ++k0) {
                    half8 a0 = *(const half8*)&xa0[fr * 136 + k0 * 32 + fo8];
                    half8 a1 = *(const half8*)&xa1[fr * 136 + k0 * 32 + fo8];
#pragma unroll
                    for (int j = 0; j < 4; ++j) {
                        acc[j] = MFMA_F16(a0, wf[(j * 4 + k0) * 2], acc[j]);
                        acc[j] = MFMA_F16(a0, wf[(j * 4 + k0) * 2 + 1], acc[j]);
                        acc[j] = MFMA_F16(a1, wf[(j * 4 + k0) * 2], acc[j]);
                    }
                }
#pragma unroll
                for (int j = 0; j < 4; ++j) {
                    int col = 64 * gg + 16 * j + fr;
#pragma unroll
                    for (int r = 0; r < 4; ++r)
                        h1buf[(qr + r) * 260 + col] = acc[j][r] + bias0[j];
                }
            }
            if (tid >= 384 && s <= 21) {
                // prefetch x(s+2) rows for next stage
#pragma unroll
                for (int q = 0; q < 4; ++q)
                    pfx[q] = *(const float4*)&xbase[(size_t)(tbase + 32 + srow + 4 * q) * 128 + sc4];
            }
        }

        // pfln prefetch for LN(s) (consumed next iteration)
        if (s >= 8 && s <= 23) {
#pragma unroll
            for (int rr = 0; rr < 2; ++rr)
                pflnN[rr] = *(const float2*)&xbase[(size_t)(tbase + 2 * w + rr) * 128 + lane * 2];
        }

        // LN(s-1) + store (all 8 waves, 2 rows each)
        if (s >= 9) {
            const int tbm = tbase - 16;
#pragma unroll
            for (int rr = 0; rr < 2; ++rr) {
                int row = 2 * w + rr;
                float2 s2v = *(const float2*)&s2buf[row * 132 + lane * 2];
                float y0 = pflnC[rr].x + s2v.x;
                float y1 = pflnC[rr].y + s2v.y;
                float sum = y0 + y1;
                float ss = y0 * y0 + y1 * y1;
#pragma unroll
                for (int off = 32; off > 0; off >>= 1) {
                    sum += __shfl_xor(sum, off, 64);
                    ss  += __shfl_xor(ss, off, 64);
                }
                float mu = sum * (1.0f / 128.0f);
                float var = ss * (1.0f / 128.0f) - mu * mu;
                float inv = rsqrtf(var + 1e-5f);
                float2 o;
                o.x = (y0 - mu) * inv * wv.x + bbv.x;
                o.y = (y1 - mu) * inv * wv.y + bbv.y;
                *(float2*)&obase[(size_t)(tbm + row) * 128 + lane * 2] = o;
            }
        }
        pflnC[0] = pflnN[0];
        pflnC[1] = pflnN[1];
        bar_lds();
    }
}

extern "C" void kernel_launch(void* const* d_in, const int* in_sizes, int n_in,
                              void* d_out, int out_size, void* d_ws, size_t ws_size,
                              hipStream_t stream)
{
    const float* x   = (const float*)d_in[0];
    const float* W1  = (const float*)d_in[1];
    const float* b1  = (const float*)d_in[2];
    const float* W2  = (const float*)d_in[3];
    const float* b2  = (const float*)d_in[4];
    const float* lnw = (const float*)d_in[5];
    const float* lnb = (const float*)d_in[6];
    float* out = (float*)d_out;

    dim3 gM(8, 32);   // 256 blocks, 1/CU
    mega_kernel<<<gM, 512, 0, stream>>>(x, W1, W2, b1, b2, lnw, lnb, out);
}

// Round 6
// 138.663 us; speedup vs baseline: 1.0466x; 1.0466x over previous
//
#include <hip/hip_runtime.h>

// B=32, T=2048, D=128, H=256. fp32 in/out. SINGLE dispatch.
// 2-phase, 2-barrier wave-specialized megakernel, grid (8,32), 512 threads.
// Chunk = 256 t (finer T-chunking fails numerically), warmup = 128 t.
// KEY CHANGE vs R3: subchunk 16 t -> 32 t. 13 iterations instead of 25:
// halves all per-iteration fixed costs (barrier rendezvous, waitcnt drains,
// chain-start LDS latencies). Each GEMM phase runs its two 16-row halves
// back-to-back with SEPARATE accumulators in the same temporal order R3 ran
// them in consecutive iterations; scans carry v across 32 steps exactly as
// across two old iterations -> bit-identical output (absmax 0.015625).
// Steady state per subchunk sc (32 t):
//   phase B: S(w0-3): scan1(sc)      | w4-5: scan2(sc-1) | w6-7: stage x(sc+1)
//   __syncthreads
//   phase A: S: GEMM2(sc)->h2        | G: GEMM1(sc+1)->h1, w6-7 pfx x(sc+2)
//            all: pfln prefetch(sc), LN(sc-1)+store
//   __syncthreads
// Weights register-persistent in shared-physical wf[32] half8
// (S: W2 2-plane split; G: W1 2-plane split) -> AGPR-resident on gfx950.
//
// LDS 101,376 B (gfx950 allows up to 160 KiB/workgroup; 1 block/CU):
//   h1buf[32*260] f32 (33,280)  h2buf[32*132] f32 (16,896)
//   s2buf[32*132] f32 (16,896)  spkbuf[32*264] fp16 (16,896)
//   xb[2][32*136] fp16 (17,408)

typedef _Float16 half8 __attribute__((ext_vector_type(8)));
typedef float f32x4 __attribute__((ext_vector_type(4)));

#define MFMA_F16(a, b, c) __builtin_amdgcn_mfma_f32_16x16x32_f16(a, b, c, 0, 0, 0)

__device__ __forceinline__ unsigned short h2u(_Float16 h) {
    union { _Float16 h; unsigned short u; } x; x.h = h; return x.u;
}

__device__ __forceinline__ void split8(float4 f0, float4 f1, half8& a, half8& b) {
    float fs[8] = {f0.x, f0.y, f0.z, f0.w, f1.x, f1.y, f1.z, f1.w};
    half8 ha, hb;
#pragma unroll
    for (int q = 0; q < 8; ++q) {
        ha[q] = (_Float16)fs[q];
        hb[q] = (_Float16)(fs[q] - (float)ha[q]);
    }
    a = ha; b = hb;
}

__global__ __launch_bounds__(512, 1) void mega_kernel(
    const float* __restrict__ X,
    const float* __restrict__ W1, const float* __restrict__ W2,
    const float* __restrict__ b1, const float* __restrict__ b2,
    const float* __restrict__ lnw, const float* __restrict__ lnb,
    float* __restrict__ out)
{
    __shared__ __align__(16) float h1buf[32 * 260];                 // 33,280 B
    __shared__ __align__(16) float h2buf[32 * 132];                 // 16,896 B
    __shared__ __align__(16) float s2buf[32 * 132];                 // 16,896 B
    __shared__ __align__(16) unsigned short spkbuf[32 * 264];       // 16,896 B
    __shared__ __align__(16) unsigned short xb[2][32 * 136];        // 17,408 B

    const int tid = threadIdx.x;
    const int lane = tid & 63;
    const int w = tid >> 6;                 // wave 0..7
    const bool isS = (tid < 256);           // S-group: waves 0-3
    const int sg = w;                       // S-wave id
    const int gg = w - 4;                   // G-wave id
    const int fr = lane & 15;
    const int fo8 = (lane >> 4) * 8;
    const int qr = (lane >> 4) * 4;
    const int b = blockIdx.y;
    const int t0 = blockIdx.x * 256;
    const int s0 = (blockIdx.x == 0) ? 4 : 0;

    const float* __restrict__ xbase = X + (size_t)b * 2048 * 128;
    float* __restrict__ obase = out + (size_t)b * 2048 * 128;

    // ---- shared-physical weight fragments (identical to R0) ----
    half8 wf[32];
    float bias0[4];
    if (isS) {
        // W2 slice: d-rows 32sg+16j+fr, j<2; wf[(j*8+ks)*2+p]
#pragma unroll
        for (int j = 0; j < 2; ++j) {
            const size_t d = (size_t)(32 * sg + 16 * j + fr) * 256;
#pragma unroll
            for (int ks = 0; ks < 8; ++ks) {
                float4 f0 = *(const float4*)&W2[d + ks * 32 + fo8];
                float4 f1 = *(const float4*)&W2[d + ks * 32 + fo8 + 4];
                split8(f0, f1, wf[(j * 8 + ks) * 2], wf[(j * 8 + ks) * 2 + 1]);
            }
            bias0[j] = b2[32 * sg + 16 * j + fr];
        }
    } else {
        // W1 slice: h-rows 64gg+16j+fr, j<4; wf[(j*4+k0)*2+p]
#pragma unroll
        for (int j = 0; j < 4; ++j) {
            const size_t n = (size_t)(64 * gg + 16 * j + fr) * 128;
#pragma unroll
            for (int k0 = 0; k0 < 4; ++k0) {
                float4 f0 = *(const float4*)&W1[n + k0 * 32 + fo8];
                float4 f1 = *(const float4*)&W1[n + k0 * 32 + fo8 + 4];
                split8(f0, f1, wf[(j * 4 + k0) * 2], wf[(j * 4 + k0) * 2 + 1]);
            }
            bias0[j] = b1[64 * gg + 16 * j + fr];
        }
    }
    const float2 wv = *(const float2*)(lnw + lane * 2);
    const float2 bbv = *(const float2*)(lnb + lane * 2);

    float v1 = 0.0f, v2 = 0.0f;
    const int d2 = (tid - 256) & 127;       // scan2 col (waves 4-5)
    const int tgs = (tid - 384) & 127;      // stage thread idx (waves 6-7)
    const int srow = tgs >> 5;              // 0..3
    const int sc4 = (tgs & 31) * 4;         // 0..124
    float4 pfx[8];
    float2 pflnC[4], pflnN[4];

    // ---- prologue: stage x(s0); GEMM1(s0); prime pfx for x(s0+1) ----
    if (tid >= 384) {
        const int tb = t0 - 128 + s0 * 32;
#pragma unroll
        for (int q = 0; q < 8; ++q) {
            float4 xv = *(const float4*)&xbase[(size_t)(tb + srow + 4 * q) * 128 + sc4];
            _Float16 a0 = (_Float16)xv.x, e0 = (_Float16)(xv.x - (float)a0);
            _Float16 a1 = (_Float16)xv.y, e1 = (_Float16)(xv.y - (float)a1);
            _Float16 a2 = (_Float16)xv.z, e2 = (_Float16)(xv.z - (float)a2);
            _Float16 a3 = (_Float16)xv.w, e3 = (_Float16)(xv.w - (float)a3);
            ushort4 ua = {h2u(a0), h2u(a1), h2u(a2), h2u(a3)};
            ushort4 ue = {h2u(e0), h2u(e1), h2u(e2), h2u(e3)};
            *(ushort4*)&xb[0][(srow + 4 * q) * 136 + sc4] = ua;
            *(ushort4*)&xb[1][(srow + 4 * q) * 136 + sc4] = ue;
        }
    }
    __syncthreads();
    if (!isS) {
        const _Float16* xa0 = (const _Float16*)&xb[0][0];
        const _Float16* xa1 = (const _Float16*)&xb[1][0];
#pragma unroll
        for (int h = 0; h < 2; ++h) {
            f32x4 acc[4];
#pragma unroll
            for (int j = 0; j < 4; ++j) acc[j] = (f32x4){0.f, 0.f, 0.f, 0.f};
#pragma unroll
            for (int k0 = 0; k0 < 4; ++k0) {
                half8 a0 = *(const half8*)&xa0[(fr + 16 * h) * 136 + k0 * 32 + fo8];
                half8 a1 = *(const half8*)&xa1[(fr + 16 * h) * 136 + k0 * 32 + fo8];
#pragma unroll
                for (int j = 0; j < 4; ++j) {
                    acc[j] = MFMA_F16(a0, wf[(j * 4 + k0) * 2], acc[j]);
                    acc[j] = MFMA_F16(a0, wf[(j * 4 + k0) * 2 + 1], acc[j]);
                    acc[j] = MFMA_F16(a1, wf[(j * 4 + k0) * 2], acc[j]);
                }
            }
#pragma unroll
            for (int j = 0; j < 4; ++j) {
                int col = 64 * gg + 16 * j + fr;
#pragma unroll
                for (int r = 0; r < 4; ++r)
                    h1buf[(qr + r + 16 * h) * 260 + col] = acc[j][r] + bias0[j];
            }
        }
        if (tid >= 384) {
            const int tb = t0 - 128 + s0 * 32 + 32;
#pragma unroll
            for (int q = 0; q < 8; ++q)
                pfx[q] = *(const float4*)&xbase[(size_t)(tb + srow + 4 * q) * 128 + sc4];
        }
    }
    __syncthreads();

    // ---- main loop: sc = s0..12 (sc=12 runs only scan2(11)/LN(11)) ----
    for (int sc = s0; sc <= 12; ++sc) {
        const int tbase = t0 - 128 + sc * 32;

        // ================= phase B =================
        if (isS) {
            if (sc <= 11) {
                // scan1(sc): h1 -> spikes (32 rows)
                float hh[32];
#pragma unroll
                for (int t = 0; t < 32; ++t) hh[t] = h1buf[t * 260 + tid];
#pragma unroll
                for (int t = 0; t < 32; ++t) {
                    float h = v1 + (hh[t] - v1) * 0.5f;
                    bool sp = (h >= 1.0f);
                    v1 = sp ? 0.0f : h;
                    spkbuf[t * 264 + tid] = sp ? (unsigned short)0x3C00 : (unsigned short)0;
                }
            }
        } else if (tid < 384) {
            if (sc > s0) {
                // scan2(sc-1): h2 -> s2 (32 rows)
                float hh[32];
#pragma unroll
                for (int t = 0; t < 32; ++t) hh[t] = h2buf[t * 132 + d2];
#pragma unroll
                for (int t = 0; t < 32; ++t) {
                    float h = v2 + (hh[t] - v2) * 0.5f;
                    bool sp = (h >= 1.0f);
                    v2 = sp ? 0.0f : h;
                    s2buf[t * 132 + d2] = sp ? 1.0f : 0.0f;
                }
            }
        } else {
            if (sc <= 10) {
                // stage x(sc+1) from pfx regs (32 rows)
#pragma unroll
                for (int q = 0; q < 8; ++q) {
                    float4 xv = pfx[q];
                    _Float16 a0 = (_Float16)xv.x, e0 = (_Float16)(xv.x - (float)a0);
                    _Float16 a1 = (_Float16)xv.y, e1 = (_Float16)(xv.y - (float)a1);
                    _Float16 a2 = (_Float16)xv.z, e2 = (_Float16)(xv.z - (float)a2);
                    _Float16 a3 = (_Float16)xv.w, e3 = (_Float16)(xv.w - (float)a3);
                    ushort4 ua = {h2u(a0), h2u(a1), h2u(a2), h2u(a3)};
                    ushort4 ue = {h2u(e0), h2u(e1), h2u(e2), h2u(e3)};
                    *(ushort4*)&xb[0][(srow + 4 * q) * 136 + sc4] = ua;
                    *(ushort4*)&xb[1][(srow + 4 * q) * 136 + sc4] = ue;
                }
            }
        }
        __syncthreads();

        // ================= phase A =================
        if (isS) {
            if (sc <= 11) {
                // GEMM2(sc): spikes @ W2 -> h2 (two 16-row halves)
                const _Float16* sp = (const _Float16*)&spkbuf[0];
#pragma unroll
                for (int h = 0; h < 2; ++h) {
                    f32x4 acc[2];
                    acc[0] = (f32x4){0.f, 0.f, 0.f, 0.f};
                    acc[1] = (f32x4){0.f, 0.f, 0.f, 0.f};
#pragma unroll
                    for (int ks = 0; ks < 8; ++ks) {
                        half8 a = *(const half8*)&sp[(fr + 16 * h) * 264 + ks * 32 + fo8];
#pragma unroll
                        for (int j = 0; j < 2; ++j) {
                            acc[j] = MFMA_F16(a, wf[(j * 8 + ks) * 2], acc[j]);
                            acc[j] = MFMA_F16(a, wf[(j * 8 + ks) * 2 + 1], acc[j]);
                        }
                    }
#pragma unroll
                    for (int j = 0; j < 2; ++j) {
                        int col = 32 * sg + 16 * j + fr;
#pragma unroll
                        for (int r = 0; r < 4; ++r)
                            h2buf[(qr + r + 16 * h) * 132 + col] = acc[j][r] + bias0[j];
                    }
                }
            }
        } else {
            if (sc <= 10) {
                // GEMM1(sc+1): x(sc+1) @ W1 -> h1 (two 16-row halves)
                const _Float16* xa0 = (const _Float16*)&xb[0][0];
                const _Float16* xa1 = (const _Float16*)&xb[1][0];
#pragma unroll
                for (int h = 0; h < 2; ++h) {
                    f32x4 acc[4];
#pragma unroll
                    for (int j = 0; j < 4; ++j) acc[j] = (f32x4){0.f, 0.f, 0.f, 0.f};
#pragma unroll
                    for (int k0 = 0; k0 < 4; ++k0) {
                        half8 a0 = *(const half8*)&xa0[(fr + 16 * h) * 136 + k0 * 32 + fo8];
                        half8 a1 = *(const half8*)&xa1[(fr + 16 * h) * 136 + k0 * 32 + fo8];
#pragma unroll
                        for (int j = 0; j < 4; ++j) {
                            acc[j] = MFMA_F16(a0, wf[(j * 4 + k0) * 2], acc[j]);
                            acc[j] = MFMA_F16(a0, wf[(j * 4 + k0) * 2 + 1], acc[j]);
                            acc[j] = MFMA_F16(a1, wf[(j * 4 + k0) * 2], acc[j]);
                        }
                    }
#pragma unroll
                    for (int j = 0; j < 4; ++j) {
                        int col = 64 * gg + 16 * j + fr;
#pragma unroll
                        for (int r = 0; r < 4; ++r)
                            h1buf[(qr + r + 16 * h) * 260 + col] = acc[j][r] + bias0[j];
                    }
                }
            }
            if (tid >= 384 && sc <= 9) {
                // prefetch x(sc+2) rows for next stage
#pragma unroll
                for (int q = 0; q < 8; ++q)
                    pfx[q] = *(const float4*)&xbase[(size_t)(tbase + 64 + srow + 4 * q) * 128 + sc4];
            }
        }

        // pfln prefetch for LN(sc) (consumed next iteration)
        if (sc >= 4 && sc <= 11) {
#pragma unroll
            for (int rr = 0; rr < 4; ++rr)
                pflnN[rr] = *(const float2*)&xbase[(size_t)(tbase + 4 * w + rr) * 128 + lane * 2];
        }

        // LN(sc-1) + store (all 8 waves, 4 rows each)
        if (sc >= 5) {
            const int tbm = tbase - 32;
#pragma unroll
            for (int rr = 0; rr < 4; ++rr) {
                int row = 4 * w + rr;
                float2 s2v = *(const float2*)&s2buf[row * 132 + lane * 2];
                float y0 = pflnC[rr].x + s2v.x;
                float y1 = pflnC[rr].y + s2v.y;
                float sum = y0 + y1;
                float ss = y0 * y0 + y1 * y1;
#pragma unroll
                for (int off = 32; off > 0; off >>= 1) {
                    sum += __shfl_xor(sum, off, 64);
                    ss  += __shfl_xor(ss, off, 64);
                }
                float mu = sum * (1.0f / 128.0f);
                float var = ss * (1.0f / 128.0f) - mu * mu;
                float inv = rsqrtf(var + 1e-5f);
                float2 o;
                o.x = (y0 - mu) * inv * wv.x + bbv.x;
                o.y = (y1 - mu) * inv * wv.y + bbv.y;
                *(float2*)&obase[(size_t)(tbm + row) * 128 + lane * 2] = o;
            }
        }
#pragma unroll
        for (int rr = 0; rr < 4; ++rr) pflnC[rr] = pflnN[rr];
        __syncthreads();
    }
}

extern "C" void kernel_launch(void* const* d_in, const int* in_sizes, int n_in,
                              void* d_out, int out_size, void* d_ws, size_t ws_size,
                              hipStream_t stream)
{
    const float* x   = (const float*)d_in[0];
    const float* W1  = (const float*)d_in[1];
    const float* b1  = (const float*)d_in[2];
    const float* W2  = (const float*)d_in[3];
    const float* b2  = (const float*)d_in[4];
    const float* lnw = (const float*)d_in[5];
    const float* lnb = (const float*)d_in[6];
    float* out = (float*)d_out;

    dim3 gM(8, 32);   // 256 blocks, 1/CU
    mega_kernel<<<gM, 512, 0, stream>>>(x, W1, W2, b1, b2, lnw, lnb, out);
}

// Round 7
// 136.322 us; speedup vs baseline: 1.0646x; 1.0172x over previous
//
#include <hip/hip_runtime.h>

// B=32, T=2048, D=128, H=256. fp32 in/out. SINGLE dispatch.
// 2-phase, 2-barrier wave-specialized megakernel, grid (8,32), 512 threads.
// Chunk = 256 t (finer T-chunking fails numerically), warmup = 128 t,
// subchunk = 32 t, 13 iterations (+1 epilogue).
// KEY CHANGE vs R6 (pure scheduling, zero arithmetic change):
//  - LN(sc-2)+store moved into phase B (2-subchunk lag, s2 double-buffered):
//    stores issue at the TOP of B and are covered by the ~700-cy scan chains
//    before the B-end barrier -> the __syncthreads vmcnt(0) drain is cheap.
//    Also drains work out of the long phase A (better phase balance).
//  - pfln/pfx prefetch issues moved to the TOP of phase A (before GEMMs):
//    ~800 cy old by the A-end barrier -> cheap drain.
// Steady state per subchunk sc (32 t):
//   phase B: all: LN(sc-2)+store | S(w0-3): scan1(sc) | w4-5: scan2(sc-1)
//            | w6-7: stage x(sc+1)
//   __syncthreads
//   phase A: all: pfln issue x(sc-1) | w6-7: pfx issue x(sc+2)
//            S: GEMM2(sc)->h2 | G: GEMM1(sc+1)->h1
//   __syncthreads
// Hazards: s2 ping-pong (scan2 writes (sc-1)&1, LN reads sc&1, disjoint);
// h1/h2/spk/xb single-buffered with >=1 barrier between write and read.
// All accumulation orders instruction-identical to R6 (absmax 0.015625).
//
// LDS 118,272 B (<= 160 KiB; 1 block/CU):
//   h1buf[32*260] f32 (33,280)  h2buf[32*132] f32 (16,896)
//   s2buf[2][32*132] f32 (33,792)  spkbuf[32*264] fp16 (16,896)
//   xb[2][32*136] fp16 (17,408)

typedef _Float16 half8 __attribute__((ext_vector_type(8)));
typedef float f32x4 __attribute__((ext_vector_type(4)));

#define MFMA_F16(a, b, c) __builtin_amdgcn_mfma_f32_16x16x32_f16(a, b, c, 0, 0, 0)

__device__ __forceinline__ unsigned short h2u(_Float16 h) {
    union { _Float16 h; unsigned short u; } x; x.h = h; return x.u;
}

__device__ __forceinline__ void split8(float4 f0, float4 f1, half8& a, half8& b) {
    float fs[8] = {f0.x, f0.y, f0.z, f0.w, f1.x, f1.y, f1.z, f1.w};
    half8 ha, hb;
#pragma unroll
    for (int q = 0; q < 8; ++q) {
        ha[q] = (_Float16)fs[q];
        hb[q] = (_Float16)(fs[q] - (float)ha[q]);
    }
    a = ha; b = hb;
}

__global__ __launch_bounds__(512, 1) void mega_kernel(
    const float* __restrict__ X,
    const float* __restrict__ W1, const float* __restrict__ W2,
    const float* __restrict__ b1, const float* __restrict__ b2,
    const float* __restrict__ lnw, const float* __restrict__ lnb,
    float* __restrict__ out)
{
    __shared__ __align__(16) float h1buf[32 * 260];                 // 33,280 B
    __shared__ __align__(16) float h2buf[32 * 132];                 // 16,896 B
    __shared__ __align__(16) float s2buf[2][32 * 132];              // 33,792 B
    __shared__ __align__(16) unsigned short spkbuf[32 * 264];       // 16,896 B
    __shared__ __align__(16) unsigned short xb[2][32 * 136];        // 17,408 B

    const int tid = threadIdx.x;
    const int lane = tid & 63;
    const int w = tid >> 6;                 // wave 0..7
    const bool isS = (tid < 256);           // S-group: waves 0-3
    const int sg = w;                       // S-wave id
    const int gg = w - 4;                   // G-wave id
    const int fr = lane & 15;
    const int fo8 = (lane >> 4) * 8;
    const int qr = (lane >> 4) * 4;
    const int b = blockIdx.y;
    const int t0 = blockIdx.x * 256;
    const int s0 = (blockIdx.x == 0) ? 4 : 0;

    const float* __restrict__ xbase = X + (size_t)b * 2048 * 128;
    float* __restrict__ obase = out + (size_t)b * 2048 * 128;

    // ---- shared-physical weight fragments (identical to R0) ----
    half8 wf[32];
    float bias0[4];
    if (isS) {
        // W2 slice: d-rows 32sg+16j+fr, j<2; wf[(j*8+ks)*2+p]
#pragma unroll
        for (int j = 0; j < 2; ++j) {
            const size_t d = (size_t)(32 * sg + 16 * j + fr) * 256;
#pragma unroll
            for (int ks = 0; ks < 8; ++ks) {
                float4 f0 = *(const float4*)&W2[d + ks * 32 + fo8];
                float4 f1 = *(const float4*)&W2[d + ks * 32 + fo8 + 4];
                split8(f0, f1, wf[(j * 8 + ks) * 2], wf[(j * 8 + ks) * 2 + 1]);
            }
            bias0[j] = b2[32 * sg + 16 * j + fr];
        }
    } else {
        // W1 slice: h-rows 64gg+16j+fr, j<4; wf[(j*4+k0)*2+p]
#pragma unroll
        for (int j = 0; j < 4; ++j) {
            const size_t n = (size_t)(64 * gg + 16 * j + fr) * 128;
#pragma unroll
            for (int k0 = 0; k0 < 4; ++k0) {
                float4 f0 = *(const float4*)&W1[n + k0 * 32 + fo8];
                float4 f1 = *(const float4*)&W1[n + k0 * 32 + fo8 + 4];
                split8(f0, f1, wf[(j * 4 + k0) * 2], wf[(j * 4 + k0) * 2 + 1]);
            }
            bias0[j] = b1[64 * gg + 16 * j + fr];
        }
    }
    const float2 wv = *(const float2*)(lnw + lane * 2);
    const float2 bbv = *(const float2*)(lnb + lane * 2);

    float v1 = 0.0f, v2 = 0.0f;
    const int d2 = (tid - 256) & 127;       // scan2 col (waves 4-5)
    const int tgs = (tid - 384) & 127;      // stage thread idx (waves 6-7)
    const int srow = tgs >> 5;              // 0..3
    const int sc4 = (tgs & 31) * 4;         // 0..124
    float4 pfx[8];
    float2 pflnC[4], pflnN[4];

    // ---- prologue: stage x(s0); GEMM1(s0); prime pfx for x(s0+1) ----
    if (tid >= 384) {
        const int tb = t0 - 128 + s0 * 32;
#pragma unroll
        for (int q = 0; q < 8; ++q) {
            float4 xv = *(const float4*)&xbase[(size_t)(tb + srow + 4 * q) * 128 + sc4];
            _Float16 a0 = (_Float16)xv.x, e0 = (_Float16)(xv.x - (float)a0);
            _Float16 a1 = (_Float16)xv.y, e1 = (_Float16)(xv.y - (float)a1);
            _Float16 a2 = (_Float16)xv.z, e2 = (_Float16)(xv.z - (float)a2);
            _Float16 a3 = (_Float16)xv.w, e3 = (_Float16)(xv.w - (float)a3);
            ushort4 ua = {h2u(a0), h2u(a1), h2u(a2), h2u(a3)};
            ushort4 ue = {h2u(e0), h2u(e1), h2u(e2), h2u(e3)};
            *(ushort4*)&xb[0][(srow + 4 * q) * 136 + sc4] = ua;
            *(ushort4*)&xb[1][(srow + 4 * q) * 136 + sc4] = ue;
        }
    }
    __syncthreads();
    if (!isS) {
        const _Float16* xa0 = (const _Float16*)&xb[0][0];
        const _Float16* xa1 = (const _Float16*)&xb[1][0];
#pragma unroll
        for (int h = 0; h < 2; ++h) {
            f32x4 acc[4];
#pragma unroll
            for (int j = 0; j < 4; ++j) acc[j] = (f32x4){0.f, 0.f, 0.f, 0.f};
#pragma unroll
            for (int k0 = 0; k0 < 4; ++k0) {
                half8 a0 = *(const half8*)&xa0[(fr + 16 * h) * 136 + k0 * 32 + fo8];
                half8 a1 = *(const half8*)&xa1[(fr + 16 * h) * 136 + k0 * 32 + fo8];
#pragma unroll
                for (int j = 0; j < 4; ++j) {
                    acc[j] = MFMA_F16(a0, wf[(j * 4 + k0) * 2], acc[j]);
                    acc[j] = MFMA_F16(a0, wf[(j * 4 + k0) * 2 + 1], acc[j]);
                    acc[j] = MFMA_F16(a1, wf[(j * 4 + k0) * 2], acc[j]);
                }
            }
#pragma unroll
            for (int j = 0; j < 4; ++j) {
                int col = 64 * gg + 16 * j + fr;
#pragma unroll
                for (int r = 0; r < 4; ++r)
                    h1buf[(qr + r + 16 * h) * 260 + col] = acc[j][r] + bias0[j];
            }
        }
        if (tid >= 384) {
            const int tb = t0 - 128 + s0 * 32 + 32;
#pragma unroll
            for (int q = 0; q < 8; ++q)
                pfx[q] = *(const float4*)&xbase[(size_t)(tb + srow + 4 * q) * 128 + sc4];
        }
    }
    __syncthreads();

    // ---- main loop: sc = s0..13 ----
    for (int sc = s0; sc <= 13; ++sc) {
        const int tbase = t0 - 128 + sc * 32;

        // ================= phase B =================
        // LN(sc-2) + store FIRST (stores covered by the scans below)
        if (sc >= 6) {
            const int tbm = tbase - 64;
            const float* s2r = &s2buf[sc & 1][0];
#pragma unroll
            for (int rr = 0; rr < 4; ++rr) {
                int row = 4 * w + rr;
                float2 s2v = *(const float2*)&s2r[row * 132 + lane * 2];
                float y0 = pflnC[rr].x + s2v.x;
                float y1 = pflnC[rr].y + s2v.y;
                float sum = y0 + y1;
                float ss = y0 * y0 + y1 * y1;
#pragma unroll
                for (int off = 32; off > 0; off >>= 1) {
                    sum += __shfl_xor(sum, off, 64);
                    ss  += __shfl_xor(ss, off, 64);
                }
                float mu = sum * (1.0f / 128.0f);
                float var = ss * (1.0f / 128.0f) - mu * mu;
                float inv = rsqrtf(var + 1e-5f);
                float2 o;
                o.x = (y0 - mu) * inv * wv.x + bbv.x;
                o.y = (y1 - mu) * inv * wv.y + bbv.y;
                *(float2*)&obase[(size_t)(tbm + row) * 128 + lane * 2] = o;
            }
        }
        if (isS) {
            if (sc <= 11) {
                // scan1(sc): h1 -> spikes (32 rows)
                float hh[32];
#pragma unroll
                for (int t = 0; t < 32; ++t) hh[t] = h1buf[t * 260 + tid];
#pragma unroll
                for (int t = 0; t < 32; ++t) {
                    float h = v1 + (hh[t] - v1) * 0.5f;
                    bool sp = (h >= 1.0f);
                    v1 = sp ? 0.0f : h;
                    spkbuf[t * 264 + tid] = sp ? (unsigned short)0x3C00 : (unsigned short)0;
                }
            }
        } else if (tid < 384) {
            if (sc > s0 && sc <= 12) {
                // scan2(sc-1): h2 -> s2[(sc-1)&1] (32 rows)
                float* s2w = &s2buf[(sc - 1) & 1][0];
                float hh[32];
#pragma unroll
                for (int t = 0; t < 32; ++t) hh[t] = h2buf[t * 132 + d2];
#pragma unroll
                for (int t = 0; t < 32; ++t) {
                    float h = v2 + (hh[t] - v2) * 0.5f;
                    bool sp = (h >= 1.0f);
                    v2 = sp ? 0.0f : h;
                    s2w[t * 132 + d2] = sp ? 1.0f : 0.0f;
                }
            }
        } else {
            if (sc <= 10) {
                // stage x(sc+1) from pfx regs (32 rows)
#pragma unroll
                for (int q = 0; q < 8; ++q) {
                    float4 xv = pfx[q];
                    _Float16 a0 = (_Float16)xv.x, e0 = (_Float16)(xv.x - (float)a0);
                    _Float16 a1 = (_Float16)xv.y, e1 = (_Float16)(xv.y - (float)a1);
                    _Float16 a2 = (_Float16)xv.z, e2 = (_Float16)(xv.z - (float)a2);
                    _Float16 a3 = (_Float16)xv.w, e3 = (_Float16)(xv.w - (float)a3);
                    ushort4 ua = {h2u(a0), h2u(a1), h2u(a2), h2u(a3)};
                    ushort4 ue = {h2u(e0), h2u(e1), h2u(e2), h2u(e3)};
                    *(ushort4*)&xb[0][(srow + 4 * q) * 136 + sc4] = ua;
                    *(ushort4*)&xb[1][(srow + 4 * q) * 136 + sc4] = ue;
                }
            }
        }
        __syncthreads();

        // ================= phase A =================
        // prefetch issues FIRST (old by the A-end barrier -> cheap drain)
        if (sc >= 5 && sc <= 12) {
            // pfln for LN(sc-1), consumed in B(sc+1): rows of x(sc-1)
#pragma unroll
            for (int rr = 0; rr < 4; ++rr)
                pflnN[rr] = *(const float2*)&xbase[(size_t)(tbase - 32 + 4 * w + rr) * 128 + lane * 2];
        }
        if (isS) {
            if (sc <= 11) {
                // GEMM2(sc): spikes @ W2 -> h2 (two 16-row halves)
                const _Float16* sp = (const _Float16*)&spkbuf[0];
#pragma unroll
                for (int h = 0; h < 2; ++h) {
                    f32x4 acc[2];
                    acc[0] = (f32x4){0.f, 0.f, 0.f, 0.f};
                    acc[1] = (f32x4){0.f, 0.f, 0.f, 0.f};
#pragma unroll
                    for (int ks = 0; ks < 8; ++ks) {
                        half8 a = *(const half8*)&sp[(fr + 16 * h) * 264 + ks * 32 + fo8];
#pragma unroll
                        for (int j = 0; j < 2; ++j) {
                            acc[j] = MFMA_F16(a, wf[(j * 8 + ks) * 2], acc[j]);
                            acc[j] = MFMA_F16(a, wf[(j * 8 + ks) * 2 + 1], acc[j]);
                        }
                    }
#pragma unroll
                    for (int j = 0; j < 2; ++j) {
                        int col = 32 * sg + 16 * j + fr;
#pragma unroll
                        for (int r = 0; r < 4; ++r)
                            h2buf[(qr + r + 16 * h) * 132 + col] = acc[j][r] + bias0[j];
                    }
                }
            }
        } else {
            if (tid >= 384 && sc <= 9) {
                // issue pfx x(sc+2) early (consumed in B(sc+1) staging)
#pragma unroll
                for (int q = 0; q < 8; ++q)
                    pfx[q] = *(const float4*)&xbase[(size_t)(tbase + 64 + srow + 4 * q) * 128 + sc4];
            }
            if (sc <= 10) {
                // GEMM1(sc+1): x(sc+1) @ W1 -> h1 (two 16-row halves)
                const _Float16* xa0 = (const _Float16*)&xb[0][0];
                const _Float16* xa1 = (const _Float16*)&xb[1][0];
#pragma unroll
                for (int h = 0; h < 2; ++h) {
                    f32x4 acc[4];
#pragma unroll
                    for (int j = 0; j < 4; ++j) acc[j] = (f32x4){0.f, 0.f, 0.f, 0.f};
#pragma unroll
                    for (int k0 = 0; k0 < 4; ++k0) {
                        half8 a0 = *(const half8*)&xa0[(fr + 16 * h) * 136 + k0 * 32 + fo8];
                        half8 a1 = *(const half8*)&xa1[(fr + 16 * h) * 136 + k0 * 32 + fo8];
#pragma unroll
                        for (int j = 0; j < 4; ++j) {
                            acc[j] = MFMA_F16(a0, wf[(j * 4 + k0) * 2], acc[j]);
                            acc[j] = MFMA_F16(a0, wf[(j * 4 + k0) * 2 + 1], acc[j]);
                            acc[j] = MFMA_F16(a1, wf[(j * 4 + k0) * 2], acc[j]);
                        }
                    }
#pragma unroll
                    for (int j = 0; j < 4; ++j) {
                        int col = 64 * gg + 16 * j + fr;
#pragma unroll
                        for (int r = 0; r < 4; ++r)
                            h1buf[(qr + r + 16 * h) * 260 + col] = acc[j][r] + bias0[j];
                    }
                }
            }
        }
#pragma unroll
        for (int rr = 0; rr < 4; ++rr) pflnC[rr] = pflnN[rr];
        __syncthreads();
    }
}

extern "C" void kernel_launch(void* const* d_in, const int* in_sizes, int n_in,
                              void* d_out, int out_size, void* d_ws, size_t ws_size,
                              hipStream_t stream)
{
    const float* x   = (const float*)d_in[0];
    const float* W1  = (const float*)d_in[1];
    const float* b1  = (const float*)d_in[2];
    const float* W2  = (const float*)d_in[3];
    const float* b2  = (const float*)d_in[4];
    const float* lnw = (const float*)d_in[5];
    const float* lnb = (const float*)d_in[6];
    float* out = (float*)d_out;

    dim3 gM(8, 32);   // 256 blocks, 1/CU
    mega_kernel<<<gM, 512, 0, stream>>>(x, W1, W2, b1, b2, lnw, lnb, out);
}

// Round 8
// 135.252 us; speedup vs baseline: 1.0730x; 1.0079x over previous
//
#include <hip/hip_runtime.h>

// B=32, T=2048, D=128, H=256. fp32 in/out. SINGLE dispatch.
// 2-phase, 2-barrier wave-specialized megakernel, grid (8,32), 512 threads.
// Chunk = 256 t (finer T-chunking fails numerically), warmup = 128 t,
// subchunk = 32 t, 13 iterations (+1 epilogue).
// KEY CHANGE vs R7 (bit-exact; layout + issue-count only):
//  - h1/h2 stored TRANSPOSED in LDS as [feature][t] with pad 36:
//    scans load 32 h-values as 8x ds_read_b128 (was 32x b32); GEMM epilogues
//    store acc as ds_write_b128 float4 (was 4x b32). Same values, same
//    order, same barriers -> bit-identical output (absmax 0.015625).
//  - s_setprio(1) around the serial scan chains (phase-B critical path;
//    wins SIMD issue arbitration vs stage/LN waves).
// Steady state per subchunk sc (32 t):
//   phase B: all: LN(sc-2)+store | S(w0-3): scan1(sc) | w4-5: scan2(sc-1)
//            | w6-7: stage x(sc+1)
//   __syncthreads
//   phase A: all: pfln issue x(sc-1) | w6-7: pfx issue x(sc+2)
//            S: GEMM2(sc)->h2T | G: GEMM1(sc+1)->h1T
//   __syncthreads
// Hazards: s2 ping-pong (scan2 writes (sc-1)&1, LN reads sc&1, disjoint);
// h1T/h2T/spk/xb single-buffered with >=1 barrier between write and read.
//
// LDS 123,392 B (<= 160 KiB; 1 block/CU):
//   h1T[256*36] f32 (36,864)  h2T[128*36] f32 (18,432)
//   s2buf[2][32*132] f32 (33,792)  spkbuf[32*264] fp16 (16,896)
//   xb[2][32*136] fp16 (17,408)

typedef _Float16 half8 __attribute__((ext_vector_type(8)));
typedef float f32x4 __attribute__((ext_vector_type(4)));

#define MFMA_F16(a, b, c) __builtin_amdgcn_mfma_f32_16x16x32_f16(a, b, c, 0, 0, 0)

__device__ __forceinline__ unsigned short h2u(_Float16 h) {
    union { _Float16 h; unsigned short u; } x; x.h = h; return x.u;
}

__device__ __forceinline__ void split8(float4 f0, float4 f1, half8& a, half8& b) {
    float fs[8] = {f0.x, f0.y, f0.z, f0.w, f1.x, f1.y, f1.z, f1.w};
    half8 ha, hb;
#pragma unroll
    for (int q = 0; q < 8; ++q) {
        ha[q] = (_Float16)fs[q];
        hb[q] = (_Float16)(fs[q] - (float)ha[q]);
    }
    a = ha; b = hb;
}

__global__ __launch_bounds__(512, 1) void mega_kernel(
    const float* __restrict__ X,
    const float* __restrict__ W1, const float* __restrict__ W2,
    const float* __restrict__ b1, const float* __restrict__ b2,
    const float* __restrict__ lnw, const float* __restrict__ lnb,
    float* __restrict__ out)
{
    __shared__ __align__(16) float h1T[256 * 36];                   // 36,864 B
    __shared__ __align__(16) float h2T[128 * 36];                   // 18,432 B
    __shared__ __align__(16) float s2buf[2][32 * 132];              // 33,792 B
    __shared__ __align__(16) unsigned short spkbuf[32 * 264];       // 16,896 B
    __shared__ __align__(16) unsigned short xb[2][32 * 136];        // 17,408 B

    const int tid = threadIdx.x;
    const int lane = tid & 63;
    const int w = tid >> 6;                 // wave 0..7
    const bool isS = (tid < 256);           // S-group: waves 0-3
    const int sg = w;                       // S-wave id
    const int gg = w - 4;                   // G-wave id
    const int fr = lane & 15;
    const int fo8 = (lane >> 4) * 8;
    const int qr = (lane >> 4) * 4;
    const int b = blockIdx.y;
    const int t0 = blockIdx.x * 256;
    const int s0 = (blockIdx.x == 0) ? 4 : 0;

    const float* __restrict__ xbase = X + (size_t)b * 2048 * 128;
    float* __restrict__ obase = out + (size_t)b * 2048 * 128;

    // ---- shared-physical weight fragments (identical to R0) ----
    half8 wf[32];
    float bias0[4];
    if (isS) {
        // W2 slice: d-rows 32sg+16j+fr, j<2; wf[(j*8+ks)*2+p]
#pragma unroll
        for (int j = 0; j < 2; ++j) {
            const size_t d = (size_t)(32 * sg + 16 * j + fr) * 256;
#pragma unroll
            for (int ks = 0; ks < 8; ++ks) {
                float4 f0 = *(const float4*)&W2[d + ks * 32 + fo8];
                float4 f1 = *(const float4*)&W2[d + ks * 32 + fo8 + 4];
                split8(f0, f1, wf[(j * 8 + ks) * 2], wf[(j * 8 + ks) * 2 + 1]);
            }
            bias0[j] = b2[32 * sg + 16 * j + fr];
        }
    } else {
        // W1 slice: h-rows 64gg+16j+fr, j<4; wf[(j*4+k0)*2+p]
#pragma unroll
        for (int j = 0; j < 4; ++j) {
            const size_t n = (size_t)(64 * gg + 16 * j + fr) * 128;
#pragma unroll
            for (int k0 = 0; k0 < 4; ++k0) {
                float4 f0 = *(const float4*)&W1[n + k0 * 32 + fo8];
                float4 f1 = *(const float4*)&W1[n + k0 * 32 + fo8 + 4];
                split8(f0, f1, wf[(j * 4 + k0) * 2], wf[(j * 4 + k0) * 2 + 1]);
            }
            bias0[j] = b1[64 * gg + 16 * j + fr];
        }
    }
    const float2 wv = *(const float2*)(lnw + lane * 2);
    const float2 bbv = *(const float2*)(lnb + lane * 2);

    float v1 = 0.0f, v2 = 0.0f;
    const int d2 = (tid - 256) & 127;       // scan2 col (waves 4-5)
    const int tgs = (tid - 384) & 127;      // stage thread idx (waves 6-7)
    const int srow = tgs >> 5;              // 0..3
    const int sc4 = (tgs & 31) * 4;         // 0..124
    float4 pfx[8];
    float2 pflnC[4], pflnN[4];

    // ---- prologue: stage x(s0); GEMM1(s0); prime pfx for x(s0+1) ----
    if (tid >= 384) {
        const int tb = t0 - 128 + s0 * 32;
#pragma unroll
        for (int q = 0; q < 8; ++q) {
            float4 xv = *(const float4*)&xbase[(size_t)(tb + srow + 4 * q) * 128 + sc4];
            _Float16 a0 = (_Float16)xv.x, e0 = (_Float16)(xv.x - (float)a0);
            _Float16 a1 = (_Float16)xv.y, e1 = (_Float16)(xv.y - (float)a1);
            _Float16 a2 = (_Float16)xv.z, e2 = (_Float16)(xv.z - (float)a2);
            _Float16 a3 = (_Float16)xv.w, e3 = (_Float16)(xv.w - (float)a3);
            ushort4 ua = {h2u(a0), h2u(a1), h2u(a2), h2u(a3)};
            ushort4 ue = {h2u(e0), h2u(e1), h2u(e2), h2u(e3)};
            *(ushort4*)&xb[0][(srow + 4 * q) * 136 + sc4] = ua;
            *(ushort4*)&xb[1][(srow + 4 * q) * 136 + sc4] = ue;
        }
    }
    __syncthreads();
    if (!isS) {
        const _Float16* xa0 = (const _Float16*)&xb[0][0];
        const _Float16* xa1 = (const _Float16*)&xb[1][0];
#pragma unroll
        for (int h = 0; h < 2; ++h) {
            f32x4 acc[4];
#pragma unroll
            for (int j = 0; j < 4; ++j) acc[j] = (f32x4){0.f, 0.f, 0.f, 0.f};
#pragma unroll
            for (int k0 = 0; k0 < 4; ++k0) {
                half8 a0 = *(const half8*)&xa0[(fr + 16 * h) * 136 + k0 * 32 + fo8];
                half8 a1 = *(const half8*)&xa1[(fr + 16 * h) * 136 + k0 * 32 + fo8];
#pragma unroll
                for (int j = 0; j < 4; ++j) {
                    acc[j] = MFMA_F16(a0, wf[(j * 4 + k0) * 2], acc[j]);
                    acc[j] = MFMA_F16(a0, wf[(j * 4 + k0) * 2 + 1], acc[j]);
                    acc[j] = MFMA_F16(a1, wf[(j * 4 + k0) * 2], acc[j]);
                }
            }
#pragma unroll
            for (int j = 0; j < 4; ++j) {
                int col = 64 * gg + 16 * j + fr;
                float4 o;
                o.x = acc[j][0] + bias0[j];
                o.y = acc[j][1] + bias0[j];
                o.z = acc[j][2] + bias0[j];
                o.w = acc[j][3] + bias0[j];
                *(float4*)&h1T[col * 36 + qr + 16 * h] = o;
            }
        }
        if (tid >= 384) {
            const int tb = t0 - 128 + s0 * 32 + 32;
#pragma unroll
            for (int q = 0; q < 8; ++q)
                pfx[q] = *(const float4*)&xbase[(size_t)(tb + srow + 4 * q) * 128 + sc4];
        }
    }
    __syncthreads();

    // ---- main loop: sc = s0..13 ----
    for (int sc = s0; sc <= 13; ++sc) {
        const int tbase = t0 - 128 + sc * 32;

        // ================= phase B =================
        // LN(sc-2) + store FIRST (stores covered by the scans below)
        if (sc >= 6) {
            const int tbm = tbase - 64;
            const float* s2r = &s2buf[sc & 1][0];
#pragma unroll
            for (int rr = 0; rr < 4; ++rr) {
                int row = 4 * w + rr;
                float2 s2v = *(const float2*)&s2r[row * 132 + lane * 2];
                float y0 = pflnC[rr].x + s2v.x;
                float y1 = pflnC[rr].y + s2v.y;
                float sum = y0 + y1;
                float ss = y0 * y0 + y1 * y1;
#pragma unroll
                for (int off = 32; off > 0; off >>= 1) {
                    sum += __shfl_xor(sum, off, 64);
                    ss  += __shfl_xor(ss, off, 64);
                }
                float mu = sum * (1.0f / 128.0f);
                float var = ss * (1.0f / 128.0f) - mu * mu;
                float inv = rsqrtf(var + 1e-5f);
                float2 o;
                o.x = (y0 - mu) * inv * wv.x + bbv.x;
                o.y = (y1 - mu) * inv * wv.y + bbv.y;
                *(float2*)&obase[(size_t)(tbm + row) * 128 + lane * 2] = o;
            }
        }
        if (isS) {
            if (sc <= 11) {
                // scan1(sc): h1T -> spikes (32 t, vector loads)
                float4 hv[8];
#pragma unroll
                for (int k = 0; k < 8; ++k)
                    hv[k] = *(const float4*)&h1T[tid * 36 + 4 * k];
                __builtin_amdgcn_s_setprio(1);
#pragma unroll
                for (int t = 0; t < 32; ++t) {
                    float hh = (t & 3) == 0 ? hv[t >> 2].x
                             : (t & 3) == 1 ? hv[t >> 2].y
                             : (t & 3) == 2 ? hv[t >> 2].z : hv[t >> 2].w;
                    float h = v1 + (hh - v1) * 0.5f;
                    bool sp = (h >= 1.0f);
                    v1 = sp ? 0.0f : h;
                    spkbuf[t * 264 + tid] = sp ? (unsigned short)0x3C00 : (unsigned short)0;
                }
                __builtin_amdgcn_s_setprio(0);
            }
        } else if (tid < 384) {
            if (sc > s0 && sc <= 12) {
                // scan2(sc-1): h2T -> s2[(sc-1)&1] (32 t, vector loads)
                float* s2w = &s2buf[(sc - 1) & 1][0];
                float4 hv[8];
#pragma unroll
                for (int k = 0; k < 8; ++k)
                    hv[k] = *(const float4*)&h2T[d2 * 36 + 4 * k];
                __builtin_amdgcn_s_setprio(1);
#pragma unroll
                for (int t = 0; t < 32; ++t) {
                    float hh = (t & 3) == 0 ? hv[t >> 2].x
                             : (t & 3) == 1 ? hv[t >> 2].y
                             : (t & 3) == 2 ? hv[t >> 2].z : hv[t >> 2].w;
                    float h = v2 + (hh - v2) * 0.5f;
                    bool sp = (h >= 1.0f);
                    v2 = sp ? 0.0f : h;
                    s2w[t * 132 + d2] = sp ? 1.0f : 0.0f;
                }
                __builtin_amdgcn_s_setprio(0);
            }
        } else {
            if (sc <= 10) {
                // stage x(sc+1) from pfx regs (32 rows)
#pragma unroll
                for (int q = 0; q < 8; ++q) {
                    float4 xv = pfx[q];
                    _Float16 a0 = (_Float16)xv.x, e0 = (_Float16)(xv.x - (float)a0);
                    _Float16 a1 = (_Float16)xv.y, e1 = (_Float16)(xv.y - (float)a1);
                    _Float16 a2 = (_Float16)xv.z, e2 = (_Float16)(xv.z - (float)a2);
                    _Float16 a3 = (_Float16)xv.w, e3 = (_Float16)(xv.w - (float)a3);
                    ushort4 ua = {h2u(a0), h2u(a1), h2u(a2), h2u(a3)};
                    ushort4 ue = {h2u(e0), h2u(e1), h2u(e2), h2u(e3)};
                    *(ushort4*)&xb[0][(srow + 4 * q) * 136 + sc4] = ua;
                    *(ushort4*)&xb[1][(srow + 4 * q) * 136 + sc4] = ue;
                }
            }
        }
        __syncthreads();

        // ================= phase A =================
        // prefetch issues FIRST (old by the A-end barrier -> cheap drain)
        if (sc >= 5 && sc <= 12) {
            // pfln for LN(sc-1), consumed in B(sc+1): rows of x(sc-1)
#pragma unroll
            for (int rr = 0; rr < 4; ++rr)
                pflnN[rr] = *(const float2*)&xbase[(size_t)(tbase - 32 + 4 * w + rr) * 128 + lane * 2];
        }
        if (isS) {
            if (sc <= 11) {
                // GEMM2(sc): spikes @ W2 -> h2T (two 16-row halves)
                const _Float16* sp = (const _Float16*)&spkbuf[0];
#pragma unroll
                for (int h = 0; h < 2; ++h) {
                    f32x4 acc[2];
                    acc[0] = (f32x4){0.f, 0.f, 0.f, 0.f};
                    acc[1] = (f32x4){0.f, 0.f, 0.f, 0.f};
#pragma unroll
                    for (int ks = 0; ks < 8; ++ks) {
                        half8 a = *(const half8*)&sp[(fr + 16 * h) * 264 + ks * 32 + fo8];
#pragma unroll
                        for (int j = 0; j < 2; ++j) {
                            acc[j] = MFMA_F16(a, wf[(j * 8 + ks) * 2], acc[j]);
                            acc[j] = MFMA_F16(a, wf[(j * 8 + ks) * 2 + 1], acc[j]);
                        }
                    }
#pragma unroll
                    for (int j = 0; j < 2; ++j) {
                        int col = 32 * sg + 16 * j + fr;
                        float4 o;
                        o.x = acc[j][0] + bias0[j];
                        o.y = acc[j][1] + bias0[j];
                        o.z = acc[j][2] + bias0[j];
                        o.w = acc[j][3] + bias0[j];
                        *(float4*)&h2T[col * 36 + qr + 16 * h] = o;
                    }
                }
            }
        } else {
            if (tid >= 384 && sc <= 9) {
                // issue pfx x(sc+2) early (consumed in B(sc+1) staging)
#pragma unroll
                for (int q = 0; q < 8; ++q)
                    pfx[q] = *(const float4*)&xbase[(size_t)(tbase + 64 + srow + 4 * q) * 128 + sc4];
            }
            if (sc <= 10) {
                // GEMM1(sc+1): x(sc+1) @ W1 -> h1T (two 16-row halves)
                const _Float16* xa0 = (const _Float16*)&xb[0][0];
                const _Float16* xa1 = (const _Float16*)&xb[1][0];
#pragma unroll
                for (int h = 0; h < 2; ++h) {
                    f32x4 acc[4];
#pragma unroll
                    for (int j = 0; j < 4; ++j) acc[j] = (f32x4){0.f, 0.f, 0.f, 0.f};
#pragma unroll
                    for (int k0 = 0; k0 < 4; ++k0) {
                        half8 a0 = *(const half8*)&xa0[(fr + 16 * h) * 136 + k0 * 32 + fo8];
                        half8 a1 = *(const half8*)&xa1[(fr + 16 * h) * 136 + k0 * 32 + fo8];
#pragma unroll
                        for (int j = 0; j < 4; ++j) {
                            acc[j] = MFMA_F16(a0, wf[(j * 4 + k0) * 2], acc[j]);
                            acc[j] = MFMA_F16(a0, wf[(j * 4 + k0) * 2 + 1], acc[j]);
                            acc[j] = MFMA_F16(a1, wf[(j * 4 + k0) * 2], acc[j]);
                        }
                    }
#pragma unroll
                    for (int j = 0; j < 4; ++j) {
                        int col = 64 * gg + 16 * j + fr;
                        float4 o;
                        o.x = acc[j][0] + bias0[j];
                        o.y = acc[j][1] + bias0[j];
                        o.z = acc[j][2] + bias0[j];
                        o.w = acc[j][3] + bias0[j];
                        *(float4*)&h1T[col * 36 + qr + 16 * h] = o;
                    }
                }
            }
        }
#pragma unroll
        for (int rr = 0; rr < 4; ++rr) pflnC[rr] = pflnN[rr];
        __syncthreads();
    }
}

extern "C" void kernel_launch(void* const* d_in, const int* in_sizes, int n_in,
                              void* d_out, int out_size, void* d_ws, size_t ws_size,
                              hipStream_t stream)
{
    const float* x   = (const float*)d_in[0];
    const float* W1  = (const float*)d_in[1];
    const float* b1  = (const float*)d_in[2];
    const float* W2  = (const float*)d_in[3];
    const float* b2  = (const float*)d_in[4];
    const float* lnw = (const float*)d_in[5];
    const float* lnb = (const float*)d_in[6];
    float* out = (float*)d_out;

    dim3 gM(8, 32);   // 256 blocks, 1/CU
    mega_kernel<<<gM, 512, 0, stream>>>(x, W1, W2, b1, b2, lnw, lnb, out);
}